// Round 17
// baseline (215.965 us; speedup 1.0000x reference)
//
#include <hip/hip_runtime.h>

#define NPOS 576      // B*oH*oW
#define KTOT 144      // KH*KW*IC
#define NOC 32
#define OCP 512       // columns per position (32 oc x 16 p)
#define NCQ 128       // column-quads per row (OCP/4)
#define RREG 22       // rows-per-thread held in registers (k = rs+4r, r<22)
#define RTOT 36       // total rows per thread (KTOT/4 slots)
#define NLDSROW 56    // rows 88..143 held in LDS as bf16x4
#define EPSF 1e-7f
#define LOG2PIF 1.83787706640934548356f

__device__ __forceinline__ unsigned short f2bf(float f) {
  unsigned int x = __builtin_bit_cast(unsigned int, f);
  unsigned int r = x + 0x7fffu + ((x >> 16) & 1u);   // round-to-nearest-even
  return (unsigned short)(r >> 16);
}
__device__ __forceinline__ float bf2f(unsigned short u) {
  unsigned int x = ((unsigned int)u) << 16;
  return __builtin_bit_cast(float, x);
}
__device__ __forceinline__ float4 unpack_bf4(uint2 u) {
  float4 v;
  v.x = bf2f((unsigned short)(u.x & 0xffffu));
  v.y = bf2f((unsigned short)(u.x >> 16));
  v.z = bf2f((unsigned short)(u.y & 0xffffu));
  v.w = bf2f((unsigned short)(u.y >> 16));
  return v;
}

// Round 17: single-V-sweep, V split 88 rows regs (f32) + 56 rows LDS (bf16).
//  - 512 thr; c=(w<<4)|(l&15), rs=l>>4: slot-reduce intra-wave (masks 16/32)
//  - vloc[22] = 88 VGPR; live ~123 <= 128 budget (waves_per_eu(4,4))
//  - LDS ~77 KB -> 2 blocks/CU (16 waves, vs r16's (2,2)-capped 8)
//  - bf16 on 39% of V: ~0.4% perturb, R6 probe bounds mu shift << threshold
__global__ __launch_bounds__(512)
__attribute__((amdgpu_waves_per_eu(4, 4)))
void em_routing(
    const float* __restrict__ Vf, const float* __restrict__ Af,
    const float* __restrict__ Bup, const float* __restrict__ Bap,
    float* __restrict__ out)
{
  const int pos = blockIdx.x;           // 0..575
  const int t   = (int)threadIdx.x;     // 0..511
  const int w   = t >> 6;               // wave 0..7
  const int l   = t & 63;               // lane
  const int c   = (w << 4) | (l & 15);  // column-quad 0..127
  const int rs  = l >> 4;               // row-slot 0..3 (intra-wave)
  const int oc  = c >> 2;               // 0..31

  __shared__ float sA[KTOT];
  __shared__ float sL[KTOT][NOC];       // logits -> weights (18 KB)
  __shared__ uint2 sV[NLDSROW][NCQ + 1];// bf16x4 rows 88..143 (+pad, ~58 KB)
  __shared__ float sX[NOC];
  __shared__ float sBase[NOC];

  const float4* __restrict__ V4 =
      (const float4*)(Vf + (size_t)pos * (KTOT * OCP));

  if (t < KTOT) sA[t] = Af[pos * KTOT + t];
  const float Bu = Bup[oc];
  const float Ba = Bap[oc];
  __syncthreads();

  // ---- pass 0a: register rows (k = rs+4r, r<22) + moment accumulation ----
  float4 vloc[RREG];
  float  s0 = 0.f;
  float4 s1 = {0.f,0.f,0.f,0.f}, s2 = {0.f,0.f,0.f,0.f};
  #pragma unroll
  for (int r = 0; r < RREG; ++r) {
    const int k = rs + 4 * r;
    vloc[r] = V4[k * NCQ + c];
    const float wk = sA[k] * (1.0f / 32.0f);
    const float4 v = vloc[r];
    s0 += wk;
    s1.x += wk * v.x; s1.y += wk * v.y; s1.z += wk * v.z; s1.w += wk * v.w;
    s2.x += wk * v.x * v.x; s2.y += wk * v.y * v.y;
    s2.z += wk * v.z * v.z; s2.w += wk * v.w * v.w;
  }
  // ---- pass 0b: LDS rows (bf16, thread-private) + moments (quantized v) ----
  #pragma unroll
  for (int r = RREG; r < RTOT; ++r) {
    const int k = rs + 4 * r;
    const float4 vr = V4[k * NCQ + c];
    uint2 u;
    u.x = (unsigned)f2bf(vr.x) | ((unsigned)f2bf(vr.y) << 16);
    u.y = (unsigned)f2bf(vr.z) | ((unsigned)f2bf(vr.w) << 16);
    sV[k - 88][c] = u;
    const float4 v = unpack_bf4(u);       // use quantized consistently
    const float wk = sA[k] * (1.0f / 32.0f);
    s0 += wk;
    s1.x += wk * v.x; s1.y += wk * v.y; s1.z += wk * v.z; s1.w += wk * v.w;
    s2.x += wk * v.x * v.x; s2.y += wk * v.y * v.y;
    s2.z += wk * v.z * v.z; s2.w += wk * v.w * v.w;
  }

#define GETV(r) ((r) < RREG ? vloc[(r)] : unpack_bf4(sV[rs + 4 * (r) - 88][c]))

  float4 mu, sig;
  float aout = 0.5f;

  for (int it = 0; it < 3; ++it) {
    const float lam = (it == 0) ? 5e-4f : (it == 1) ? 9.75e-4f : 1.42625e-3f;

    // ---- cross-row-slot allreduce (intra-wave: masks 16, 32) ----
    #pragma unroll
    for (int m = 16; m <= 32; m <<= 1) {
      s0   += __shfl_xor(s0,   m);
      s1.x += __shfl_xor(s1.x, m); s1.y += __shfl_xor(s1.y, m);
      s1.z += __shfl_xor(s1.z, m); s1.w += __shfl_xor(s1.w, m);
      s2.x += __shfl_xor(s2.x, m); s2.y += __shfl_xor(s2.y, m);
      s2.z += __shfl_xor(s2.z, m); s2.w += __shfl_xor(s2.w, m);
    }

    const float inv = 1.0f / (s0 + EPSF);
    mu.x = s1.x * inv; mu.y = s1.y * inv; mu.z = s1.z * inv; mu.w = s1.w * inv;
    sig.x = fmaxf(s2.x * inv - mu.x * mu.x, 1e-30f);
    sig.y = fmaxf(s2.y * inv - mu.y * mu.y, 1e-30f);
    sig.z = fmaxf(s2.z * inv - mu.z * mu.z, 1e-30f);
    sig.w = fmaxf(s2.w * inv - mu.w * mu.w, 1e-30f);

    // L = sum over 16 p of log(sigma): own 4 + p-group butterfly (l^1, l^2)
    float Lown = logf(sig.x) + logf(sig.y) + logf(sig.z) + logf(sig.w);
    float L1 = Lown + __shfl_xor(Lown, 1);
    const float L = L1 + __shfl_xor(L1, 2);

    const float x = lam * (Ba - s0 * (16.0f * Bu + 0.5f * L));
    if (rs == 0 && (l & 3) == 0) sX[oc] = x;
    __syncthreads();                       // B-x
    float ss = 0.f;
    #pragma unroll
    for (int j = 0; j < NOC; ++j) ss += sX[j] * sX[j];
    const float nrm = fmaxf(sqrtf(ss), 1e-12f);
    aout = 1.0f / (1.0f + expf(-x / nrm));

    if (it == 2) break;                    // final E-step dead in reference

    float4 c0q;
    c0q.x = 1.0f / (2.0f * sig.x + EPSF);
    c0q.y = 1.0f / (2.0f * sig.y + EPSF);
    c0q.z = 1.0f / (2.0f * sig.z + EPSF);
    c0q.w = 1.0f / (2.0f * sig.w + EPSF);
    if (rs == 0 && (l & 3) == 0)
      sBase[oc] = logf(aout) + (-0.5f * (16.0f * LOG2PIF + L) + EPSF);
    __syncthreads();                       // B-base

    // ---- logits for all 144 rows (regs + LDS-bf16) ----
    #pragma unroll
    for (int r = 0; r < RTOT; ++r) {
      const float4 v = GETV(r);
      const float dx = v.x - mu.x, dy = v.y - mu.y,
                  dz = v.z - mu.z, dw = v.w - mu.w;
      float q = dx * dx * c0q.x + dy * dy * c0q.y
              + dz * dz * c0q.z + dw * dw * c0q.w;
      q += __shfl_xor(q, 1);
      q += __shfl_xor(q, 2);
      if ((l & 3) == 0) sL[rs + 4 * r][oc] = q;
    }
    __syncthreads();                       // B-logit

    // ---- softmax over oc per row (4608 items = 512 x 9), fold a[k] ----
    #pragma unroll
    for (int j = 0; j < 9; ++j) {
      const int idx = t + 512 * j;
      const int kl = idx >> 5, o = idx & 31;
      const float val = sBase[o] - sL[kl][o];
      float mx = val;
      #pragma unroll
      for (int m = 1; m < 32; m <<= 1) mx = fmaxf(mx, __shfl_xor(mx, m, 32));
      const float e = expf(val - mx);
      float sum = e;
      #pragma unroll
      for (int m = 1; m < 32; m <<= 1) sum += __shfl_xor(sum, m, 32);
      sL[kl][o] = e * (sA[kl] / sum);
    }
    __syncthreads();                       // B-weights

    // ---- next-iteration moments (regs + LDS-bf16) ----
    s0 = 0.f;
    s1.x = s1.y = s1.z = s1.w = 0.f;
    s2.x = s2.y = s2.z = s2.w = 0.f;
    #pragma unroll
    for (int r = 0; r < RTOT; ++r) {
      const float wk = sL[rs + 4 * r][oc];
      const float4 v = GETV(r);
      s0 += wk;
      s1.x += wk * v.x; s1.y += wk * v.y; s1.z += wk * v.z; s1.w += wk * v.w;
      s2.x += wk * v.x * v.x; s2.y += wk * v.y * v.y;
      s2.z += wk * v.z * v.z; s2.w += wk * v.w * v.w;
    }
  }

  // ---- outputs (f32): mu [0:294912] | a_out [294912:313344] | sigma [...] ----
  if (rs == 0) {
    float4* __restrict__ out4 = (float4*)out;
    out4[(size_t)pos * NCQ + c]          = mu;   // mu block
    out4[78336u + (size_t)pos * NCQ + c] = sig;  // sigma block (313344/4)
    if ((l & 3) == 0) out[294912u + (size_t)pos * NOC + oc] = aout;
  }
}

extern "C" void kernel_launch(void* const* d_in, const int* in_sizes, int n_in,
                              void* d_out, int out_size, void* d_ws, size_t ws_size,
                              hipStream_t stream) {
  em_routing<<<NPOS, 512, 0, stream>>>((const float*)d_in[0], (const float*)d_in[1],
                                       (const float*)d_in[2], (const float*)d_in[3],
                                       (float*)d_out);
}

// Round 18
// 106.383 us; speedup vs baseline: 2.0301x; 2.0301x over previous
//
#include <hip/hip_runtime.h>

#define NPOS 576      // B*oH*oW
#define KTOT 144      // KH*KW*IC
#define NOC 32
#define OCP 512       // columns per position (32 oc x 16 p)
#define NCQ 128       // column-quads per row (OCP/4)
#define RREG 22       // rows-per-thread in registers (k = rs+4r, r<22)
#define RTOT 36       // total rows per thread (KTOT/4 slots)
#define NLDSROW 56    // rows 88..143 in LDS as bf16x4 (two uint planes)
#define SVS (NCQ + 1) // sV plane stride in words: 129 (odd -> all 32 banks)
#define EPSF 1e-7f
#define LOG2PIF 1.83787706640934548356f

__device__ __forceinline__ unsigned short f2bf(float f) {
  unsigned int x = __builtin_bit_cast(unsigned int, f);
  unsigned int r = x + 0x7fffu + ((x >> 16) & 1u);   // round-to-nearest-even
  return (unsigned short)(r >> 16);
}
__device__ __forceinline__ float bf2f(unsigned short u) {
  unsigned int x = ((unsigned int)u) << 16;
  return __builtin_bit_cast(float, x);
}
__device__ __forceinline__ float4 unpack_bf4(unsigned lo, unsigned hi) {
  float4 v;
  v.x = bf2f((unsigned short)(lo & 0xffffu));
  v.y = bf2f((unsigned short)(lo >> 16));
  v.z = bf2f((unsigned short)(hi & 0xffffu));
  v.w = bf2f((unsigned short)(hi >> 16));
  return v;
}

// Round 18: r17 structure under the ONLY attribute that yields a 128-VGPR
// budget on this toolchain (empirical rule: budget = 256/waves_per_eu_min;
// (2,2)->128 proven in r16, (4,4)->64 proven in r14/r15/r17).
//  - 512 thr; c=(w<<4)|(l&15), rs=l>>4 (slot reduce intra-wave, masks 16/32)
//  - V: 22 rows/thread f32 regs (88 VGPR) + 56 rows bf16 LDS (two uint
//    planes, odd stride 129 -> no even-bank aliasing)
//  - LDS ~77 KB -> 2 blocks/CU = 16 waves/CU (2x r16's occupancy)
__global__ __launch_bounds__(512)
__attribute__((amdgpu_waves_per_eu(2, 2)))
void em_routing(
    const float* __restrict__ Vf, const float* __restrict__ Af,
    const float* __restrict__ Bup, const float* __restrict__ Bap,
    float* __restrict__ out)
{
  const int pos = blockIdx.x;           // 0..575
  const int t   = (int)threadIdx.x;     // 0..511
  const int w   = t >> 6;               // wave 0..7
  const int l   = t & 63;               // lane
  const int c   = (w << 4) | (l & 15);  // column-quad 0..127
  const int rs  = l >> 4;               // row-slot 0..3 (intra-wave)
  const int oc  = c >> 2;               // 0..31

  __shared__ float    sA[KTOT];
  __shared__ float    sL[KTOT][NOC];    // logits -> weights (18 KB)
  __shared__ unsigned sVlo[NLDSROW][SVS]; // bf16 pair (x,y), ~29 KB
  __shared__ unsigned sVhi[NLDSROW][SVS]; // bf16 pair (z,w), ~29 KB
  __shared__ float    sX[NOC];
  __shared__ float    sBase[NOC];

  const float4* __restrict__ V4 =
      (const float4*)(Vf + (size_t)pos * (KTOT * OCP));

  if (t < KTOT) sA[t] = Af[pos * KTOT + t];
  const float Bu = Bup[oc];
  const float Ba = Bap[oc];
  __syncthreads();

  // ---- pass 0a: register rows + moment accumulation ----
  float4 vloc[RREG];
  float  s0 = 0.f;
  float4 s1 = {0.f,0.f,0.f,0.f}, s2 = {0.f,0.f,0.f,0.f};
  #pragma unroll
  for (int r = 0; r < RREG; ++r) {
    const int k = rs + 4 * r;
    vloc[r] = V4[k * NCQ + c];
    const float wk = sA[k] * (1.0f / 32.0f);
    const float4 v = vloc[r];
    s0 += wk;
    s1.x += wk * v.x; s1.y += wk * v.y; s1.z += wk * v.z; s1.w += wk * v.w;
    s2.x += wk * v.x * v.x; s2.y += wk * v.y * v.y;
    s2.z += wk * v.z * v.z; s2.w += wk * v.w * v.w;
  }
  // ---- pass 0b: LDS rows (bf16, thread-private cells) + moments ----
  #pragma unroll
  for (int r = RREG; r < RTOT; ++r) {
    const int k = rs + 4 * r;
    const float4 vr = V4[k * NCQ + c];
    const unsigned lo = (unsigned)f2bf(vr.x) | ((unsigned)f2bf(vr.y) << 16);
    const unsigned hi = (unsigned)f2bf(vr.z) | ((unsigned)f2bf(vr.w) << 16);
    sVlo[k - 88][c] = lo;
    sVhi[k - 88][c] = hi;
    const float4 v = unpack_bf4(lo, hi);  // use quantized consistently
    const float wk = sA[k] * (1.0f / 32.0f);
    s0 += wk;
    s1.x += wk * v.x; s1.y += wk * v.y; s1.z += wk * v.z; s1.w += wk * v.w;
    s2.x += wk * v.x * v.x; s2.y += wk * v.y * v.y;
    s2.z += wk * v.z * v.z; s2.w += wk * v.w * v.w;
  }

#define GETV(r) ((r) < RREG ? vloc[(r)] \
                 : unpack_bf4(sVlo[rs + 4 * (r) - 88][c], sVhi[rs + 4 * (r) - 88][c]))

  float4 mu, sig;
  float aout = 0.5f;

  for (int it = 0; it < 3; ++it) {
    const float lam = (it == 0) ? 5e-4f : (it == 1) ? 9.75e-4f : 1.42625e-3f;

    // ---- cross-row-slot allreduce (intra-wave: masks 16, 32) ----
    #pragma unroll
    for (int m = 16; m <= 32; m <<= 1) {
      s0   += __shfl_xor(s0,   m);
      s1.x += __shfl_xor(s1.x, m); s1.y += __shfl_xor(s1.y, m);
      s1.z += __shfl_xor(s1.z, m); s1.w += __shfl_xor(s1.w, m);
      s2.x += __shfl_xor(s2.x, m); s2.y += __shfl_xor(s2.y, m);
      s2.z += __shfl_xor(s2.z, m); s2.w += __shfl_xor(s2.w, m);
    }

    const float inv = 1.0f / (s0 + EPSF);
    mu.x = s1.x * inv; mu.y = s1.y * inv; mu.z = s1.z * inv; mu.w = s1.w * inv;
    sig.x = fmaxf(s2.x * inv - mu.x * mu.x, 1e-30f);
    sig.y = fmaxf(s2.y * inv - mu.y * mu.y, 1e-30f);
    sig.z = fmaxf(s2.z * inv - mu.z * mu.z, 1e-30f);
    sig.w = fmaxf(s2.w * inv - mu.w * mu.w, 1e-30f);

    // L = sum over 16 p of log(sigma): own 4 + p-group butterfly (l^1, l^2)
    float Lown = logf(sig.x) + logf(sig.y) + logf(sig.z) + logf(sig.w);
    float L1 = Lown + __shfl_xor(Lown, 1);
    const float L = L1 + __shfl_xor(L1, 2);

    const float x = lam * (Ba - s0 * (16.0f * Bu + 0.5f * L));
    if (rs == 0 && (l & 3) == 0) sX[oc] = x;
    __syncthreads();                       // B-x
    float ss = 0.f;
    #pragma unroll
    for (int j = 0; j < NOC; ++j) ss += sX[j] * sX[j];
    const float nrm = fmaxf(sqrtf(ss), 1e-12f);
    aout = 1.0f / (1.0f + expf(-x / nrm));

    if (it == 2) break;                    // final E-step dead in reference

    float4 c0q;
    c0q.x = 1.0f / (2.0f * sig.x + EPSF);
    c0q.y = 1.0f / (2.0f * sig.y + EPSF);
    c0q.z = 1.0f / (2.0f * sig.z + EPSF);
    c0q.w = 1.0f / (2.0f * sig.w + EPSF);
    if (rs == 0 && (l & 3) == 0)
      sBase[oc] = logf(aout) + (-0.5f * (16.0f * LOG2PIF + L) + EPSF);
    __syncthreads();                       // B-base

    // ---- logits for all 144 rows (regs + LDS-bf16) ----
    #pragma unroll
    for (int r = 0; r < RTOT; ++r) {
      const float4 v = GETV(r);
      const float dx = v.x - mu.x, dy = v.y - mu.y,
                  dz = v.z - mu.z, dw = v.w - mu.w;
      float q = dx * dx * c0q.x + dy * dy * c0q.y
              + dz * dz * c0q.z + dw * dw * c0q.w;
      q += __shfl_xor(q, 1);
      q += __shfl_xor(q, 2);
      if ((l & 3) == 0) sL[rs + 4 * r][oc] = q;
    }
    __syncthreads();                       // B-logit

    // ---- softmax over oc per row (4608 items = 512 x 9), fold a[k] ----
    #pragma unroll
    for (int j = 0; j < 9; ++j) {
      const int idx = t + 512 * j;
      const int kl = idx >> 5, o = idx & 31;
      const float val = sBase[o] - sL[kl][o];
      float mx = val;
      #pragma unroll
      for (int m = 1; m < 32; m <<= 1) mx = fmaxf(mx, __shfl_xor(mx, m, 32));
      const float e = expf(val - mx);
      float sum = e;
      #pragma unroll
      for (int m = 1; m < 32; m <<= 1) sum += __shfl_xor(sum, m, 32);
      sL[kl][o] = e * (sA[kl] / sum);
    }
    __syncthreads();                       // B-weights

    // ---- next-iteration moments (regs + LDS-bf16) ----
    s0 = 0.f;
    s1.x = s1.y = s1.z = s1.w = 0.f;
    s2.x = s2.y = s2.z = s2.w = 0.f;
    #pragma unroll
    for (int r = 0; r < RTOT; ++r) {
      const float wk = sL[rs + 4 * r][oc];
      const float4 v = GETV(r);
      s0 += wk;
      s1.x += wk * v.x; s1.y += wk * v.y; s1.z += wk * v.z; s1.w += wk * v.w;
      s2.x += wk * v.x * v.x; s2.y += wk * v.y * v.y;
      s2.z += wk * v.z * v.z; s2.w += wk * v.w * v.w;
    }
  }

  // ---- outputs (f32): mu [0:294912] | a_out [294912:313344] | sigma [...] ----
  if (rs == 0) {
    float4* __restrict__ out4 = (float4*)out;
    out4[(size_t)pos * NCQ + c]          = mu;   // mu block
    out4[78336u + (size_t)pos * NCQ + c] = sig;  // sigma block (313344/4)
    if ((l & 3) == 0) out[294912u + (size_t)pos * NOC + oc] = aout;
  }
}

extern "C" void kernel_launch(void* const* d_in, const int* in_sizes, int n_in,
                              void* d_out, int out_size, void* d_ws, size_t ws_size,
                              hipStream_t stream) {
  em_routing<<<NPOS, 512, 0, stream>>>((const float*)d_in[0], (const float*)d_in[1],
                                       (const float*)d_in[2], (const float*)d_in[3],
                                       (float*)d_out);
}